// Round 19
// baseline (367.707 us; speedup 1.0000x reference)
//
#include <hip/hip_runtime.h>
#include <math.h>

#define NN 5000
#define NE 160000
#define NF 16
#define KS 640      // k per split (8 splits: 7x640 + 520)
#define WTS 648     // LDS k-stride (bf16): 324 words, %32=4 -> 2-way alias = free
#define CAP 128     // per-node edge bucket capacity (max in-deg ~65 @ lambda=32)
#define SCB 625     // scatter-role blocks (625*256 = 160000 = NE exact)
#define GMB 632     // gemm-role blocks (79 x-tiles * 8 k-splits)

typedef __attribute__((ext_vector_type(8))) short bf16x8;  // 4 VGPRs
typedef __attribute__((ext_vector_type(4))) float f32x4;   // MFMA acc

// ws layout (bytes):
// [0,       20000)   cur   : per-node cursor -> in-degree after scatter (zeroed)
// [20000,   340000)  h1    : x@W1 (split-k atomics -> zeroed)
// [340000,  2900000) slots : bucketed edge sources, slots[d*CAP+pos]=src
// [2900000, 3220000) a1    : relu(agg1(h1)+b1)

__device__ __forceinline__ short f2bf(float f) {  // RNE f32->bf16
  union { float f; unsigned u; } v; v.f = f;
  unsigned r = v.u + 0x7FFFu + ((v.u >> 16) & 1u);
  return (short)(r >> 16);
}

// Merged kernel: blocks [0,SCB) bucket edges by dst; blocks [SCB, SCB+GMB)
// compute h1 = x @ W1 via mfma_f32_16x16x32_bf16 (fp32 acc), split-k x8.
__global__ __launch_bounds__(256) void k_gemm_scat(const float* __restrict__ x,
                                                   const float* __restrict__ w1,
                                                   float* __restrict__ h1,
                                                   const int* __restrict__ src,
                                                   const int* __restrict__ dst,
                                                   int* __restrict__ cur,
                                                   int* __restrict__ slots) {
  __shared__ short wt[NF * WTS];  // 20736 B (unused by scatter role)
  const int bid = blockIdx.x;
  const int tid = threadIdx.x;

  if (bid < SCB) {                // ---- scatter role ----
    const int e = bid * 256 + tid;
    if (e < NE) {
      const int d = dst[e];
      const int pos = atomicAdd(&cur[d], 1);
      if (pos < CAP) slots[d * CAP + pos] = src[e];
    }
    return;                       // uniform per block; no barrier crossed
  }

  // ---- gemm role ----
  const int gb = bid - SCB;       // 0..631
  const int bx = gb % 79;
  const int by = gb / 79;
  const int lane = tid & 63;
  const int wv = tid >> 6;
  const int kb = by * KS;
  const int klen = (NN - kb < KS) ? (NN - kb) : KS;   // 640 or 520
  const int nsteps = (klen + 31) >> 5;                // 20 or 17

  // Stage W1[kb..kb+KS) -> wt[n][kk] transposed bf16, zero-padded past NN.
  for (int kk = tid; kk < KS; kk += 256) {
    const int kg = kb + kk;
    if (kg < NN) {
      const float4* __restrict__ wr = (const float4*)(w1 + (size_t)kg * NF);
      const float4 a = wr[0], b = wr[1], c = wr[2], d = wr[3];
      wt[0 * WTS + kk] = f2bf(a.x);  wt[1 * WTS + kk] = f2bf(a.y);
      wt[2 * WTS + kk] = f2bf(a.z);  wt[3 * WTS + kk] = f2bf(a.w);
      wt[4 * WTS + kk] = f2bf(b.x);  wt[5 * WTS + kk] = f2bf(b.y);
      wt[6 * WTS + kk] = f2bf(b.z);  wt[7 * WTS + kk] = f2bf(b.w);
      wt[8 * WTS + kk] = f2bf(c.x);  wt[9 * WTS + kk] = f2bf(c.y);
      wt[10 * WTS + kk] = f2bf(c.z); wt[11 * WTS + kk] = f2bf(c.w);
      wt[12 * WTS + kk] = f2bf(d.x); wt[13 * WTS + kk] = f2bf(d.y);
      wt[14 * WTS + kk] = f2bf(d.z); wt[15 * WTS + kk] = f2bf(d.w);
    } else {
#pragma unroll
      for (int n = 0; n < NF; ++n) wt[n * WTS + kk] = 0;
    }
  }
  __syncthreads();

  const int tile = bx * 4 + wv;   // 0..315 (313 real)
  const int m0 = tile * 16;
  int arow = m0 + (lane & 15);
  if (arow > NN - 1) arow = NN - 1;       // clamp addr; write guarded below
  const float* __restrict__ xr = x + (size_t)arow * NN + kb;
  const int quad = lane >> 4;
  const short* __restrict__ bp = &wt[(lane & 15) * WTS + quad * 8];

  f32x4 acc = {0.f, 0.f, 0.f, 0.f};
  for (int s = 0; s < nsteps; ++s) {
    const int k0 = s * 32 + quad * 8;     // offset within split (8-aligned)
    bf16x8 a;
    if (kb + k0 < NN) {                   // whole 8-chunk valid (NN%8==0)
      const float4 xa = *(const float4*)(xr + k0);
      const float4 xb = *(const float4*)(xr + k0 + 4);
      a[0] = f2bf(xa.x); a[1] = f2bf(xa.y); a[2] = f2bf(xa.z); a[3] = f2bf(xa.w);
      a[4] = f2bf(xb.x); a[5] = f2bf(xb.y); a[6] = f2bf(xb.z); a[7] = f2bf(xb.w);
    } else {
#pragma unroll
      for (int j = 0; j < 8; ++j) a[j] = 0;
    }
    const bf16x8 b = *(const bf16x8*)(bp + s * 32);  // ds_read_b128
    acc = __builtin_amdgcn_mfma_f32_16x16x32_bf16(a, b, acc, 0, 0, 0);
  }

  const int col = lane & 15;
#pragma unroll
  for (int r = 0; r < 4; ++r) {
    const int orow = m0 + quad * 4 + r;
    if (orow < NN) atomicAdd(&h1[orow * NF + col], acc[r]);
  }
}

// Layer-1 aggregation (gather, no atomics), fused bias+ReLU:
//   a1[v][j] = relu(inv[v]*sum_s inv[s]*h1[s][j] + inv[v]^2*h1[v][j] + b1[j])
__global__ __launch_bounds__(256) void k_gather1(const int* __restrict__ slots,
                                                 const int* __restrict__ cnt,
                                                 const float* __restrict__ bias,
                                                 const float* __restrict__ hin,
                                                 float* __restrict__ outp) {
  const int tid = threadIdx.x;
  const int lane = tid & 63;
  const int wv = tid >> 6;
  const int v = blockIdx.x * 4 + wv;
  if (v >= NN) return;
  const int j = lane & 15;
  const int eg = lane >> 4;                 // edge subgroup 0..3
  int deg = cnt[v];
  if (deg > CAP) deg = CAP;
  const int* __restrict__ sl = slots + v * CAP;

  float acc = 0.f;
  int base = 0;
  for (; base + 8 <= deg; base += 8) {      // 2 independent chains per iter
    const int s0 = sl[base + eg];
    const int s1 = sl[base + 4 + eg];
    const float iv0 = rsqrtf((float)cnt[s0] + 1.0f);
    const float iv1 = rsqrtf((float)cnt[s1] + 1.0f);
    acc += iv0 * hin[s0 * NF + j];
    acc += iv1 * hin[s1 * NF + j];
  }
  for (; base < deg; base += 4) {
    const int idx = base + eg;
    if (idx < deg) {
      const int s = sl[idx];
      acc += rsqrtf((float)cnt[s] + 1.0f) * hin[s * NF + j];
    }
  }
  acc += __shfl_xor(acc, 16);
  acc += __shfl_xor(acc, 32);

  if (lane < 16) {
    const float ivv = rsqrtf((float)deg + 1.0f);
    float r = ivv * acc + ivv * ivv * hin[v * NF + j];
    outp[v * NF + j] = fmaxf(r + bias[j], 0.f);
  }
}

// Fused layer-2 aggregation + final GEMM + log_softmax. 4 rows per block,
// 512 threads. k-OUTER loop: per k, read 4 uniform g values from LDS
// (broadcast) + 3 float4 w2 loads, FMA into z[48]. No g[4][16] register
// cache -> peak live state ~85 VGPR, fits the allocator's 128 cap WITHOUT
// spill (rounds 16/17: 112+ live -> 20-reg spill -> 300 MB scratch, 134us;
// launch_bounds(512,2) hint was ignored by the allocator).
__global__ __launch_bounds__(512) void k_final6(const int* __restrict__ slots,
                                                const int* __restrict__ cnt,
                                                const float* __restrict__ a1,
                                                const float* __restrict__ w2,
                                                const float* __restrict__ b2,
                                                float* __restrict__ out) {
  __shared__ float pp[8][NF];       // per-wave gather partials
  __shared__ float gsh[4 * NF];
  __shared__ float red[8 * 4];
  __shared__ float rowmax[4];
  __shared__ float rowoff[4];
  const int tid = threadIdx.x;
  const int lane = tid & 63;
  const int wv = tid >> 6;          // 0..7
  const int row0 = blockIdx.x * 4;

  // ---- phase 1: gather g2 rows (2 waves/node, 8 edge-subgroups each) ----
  {
    const int r = wv >> 1;                          // node 0..3
    const int v = row0 + r;
    const int j = lane & 15;
    const int sg = ((wv & 1) << 2) | (lane >> 4);   // 0..7, stride 8
    int deg = cnt[v];
    if (deg > CAP) deg = CAP;
    const int* __restrict__ sl = slots + v * CAP;
    float acc = 0.f;
    for (int idx = sg; idx < deg; idx += 8) {
      const int s = sl[idx];
      acc += rsqrtf((float)cnt[s] + 1.0f) * a1[s * NF + j];
    }
    acc += __shfl_xor(acc, 16);
    acc += __shfl_xor(acc, 32);
    if (lane < 16) pp[wv][j] = acc;
  }
  __syncthreads();
  if (tid < 64) {
    const int r = tid >> 4, j = tid & 15;
    const int v = row0 + r;
    int deg = cnt[v];
    if (deg > CAP) deg = CAP;
    const float ivv = rsqrtf((float)deg + 1.0f);
    const float acc = pp[r * 2 + 0][j] + pp[r * 2 + 1][j];
    gsh[r * NF + j] = ivv * acc + ivv * ivv * a1[v * NF + j];
  }
  __syncthreads();

  // ---- phase 2: z = g2 @ W2 + b2; k outer, 3 col-chunks inner ----
  const int c0 = tid * 4;               // [0, 2048)
  const int c1 = 2048 + tid * 4;        // [2048, 4096)
  const int c2 = 4096 + tid * 4;        // [4096, 5000) for tid<226 (226*4=904)
  const bool act2 = (tid < 226);

  float zA[4][4], zB[4][4], zC[4][4];
  {
    const float4 bA = *(const float4*)(b2 + c0);
    const float4 bB = *(const float4*)(b2 + c1);
#pragma unroll
    for (int r = 0; r < 4; ++r) {
      zA[r][0] = bA.x; zA[r][1] = bA.y; zA[r][2] = bA.z; zA[r][3] = bA.w;
      zB[r][0] = bB.x; zB[r][1] = bB.y; zB[r][2] = bB.z; zB[r][3] = bB.w;
    }
    if (act2) {
      const float4 bC = *(const float4*)(b2 + c2);
#pragma unroll
      for (int r = 0; r < 4; ++r) {
        zC[r][0] = bC.x; zC[r][1] = bC.y; zC[r][2] = bC.z; zC[r][3] = bC.w;
      }
    }
  }
#pragma unroll
  for (int k = 0; k < NF; ++k) {
    float gr[4];
#pragma unroll
    for (int r = 0; r < 4; ++r) gr[r] = gsh[r * NF + k];   // uniform ds_read
    const float* __restrict__ wrow = w2 + (size_t)k * NN;
    const float4 wA = *(const float4*)(wrow + c0);
    const float4 wB = *(const float4*)(wrow + c1);
#pragma unroll
    for (int r = 0; r < 4; ++r) {
      zA[r][0] = fmaf(gr[r], wA.x, zA[r][0]);
      zA[r][1] = fmaf(gr[r], wA.y, zA[r][1]);
      zA[r][2] = fmaf(gr[r], wA.z, zA[r][2]);
      zA[r][3] = fmaf(gr[r], wA.w, zA[r][3]);
      zB[r][0] = fmaf(gr[r], wB.x, zB[r][0]);
      zB[r][1] = fmaf(gr[r], wB.y, zB[r][1]);
      zB[r][2] = fmaf(gr[r], wB.z, zB[r][2]);
      zB[r][3] = fmaf(gr[r], wB.w, zB[r][3]);
    }
    if (act2) {
      const float4 wC = *(const float4*)(wrow + c2);
#pragma unroll
      for (int r = 0; r < 4; ++r) {
        zC[r][0] = fmaf(gr[r], wC.x, zC[r][0]);
        zC[r][1] = fmaf(gr[r], wC.y, zC[r][1]);
        zC[r][2] = fmaf(gr[r], wC.z, zC[r][2]);
        zC[r][3] = fmaf(gr[r], wC.w, zC[r][3]);
      }
    }
  }

  // block-wide row max
  float mx[4];
#pragma unroll
  for (int r = 0; r < 4; ++r) {
    float m = fmaxf(fmaxf(zA[r][0], zA[r][1]), fmaxf(zA[r][2], zA[r][3]));
    m = fmaxf(m, fmaxf(fmaxf(zB[r][0], zB[r][1]), fmaxf(zB[r][2], zB[r][3])));
    if (act2)
      m = fmaxf(m, fmaxf(fmaxf(zC[r][0], zC[r][1]), fmaxf(zC[r][2], zC[r][3])));
    for (int off = 32; off; off >>= 1) m = fmaxf(m, __shfl_xor(m, off));
    mx[r] = m;
  }
  if (lane == 0) {
#pragma unroll
    for (int r = 0; r < 4; ++r) red[wv * 4 + r] = mx[r];
  }
  __syncthreads();
  if (tid < 4) {
    float m = red[tid];
#pragma unroll
    for (int w = 1; w < 8; ++w) m = fmaxf(m, red[w * 4 + tid]);
    rowmax[tid] = m;
  }
  __syncthreads();

  // block-wide row sum of exp(z - rowmax), z from registers
  {
    const float rms[4] = {rowmax[0], rowmax[1], rowmax[2], rowmax[3]};
    float sm[4];
#pragma unroll
    for (int r = 0; r < 4; ++r) {
      float s = __expf(zA[r][0] - rms[r]) + __expf(zA[r][1] - rms[r]) +
                __expf(zA[r][2] - rms[r]) + __expf(zA[r][3] - rms[r]);
      s += __expf(zB[r][0] - rms[r]) + __expf(zB[r][1] - rms[r]) +
           __expf(zB[r][2] - rms[r]) + __expf(zB[r][3] - rms[r]);
      if (act2)
        s += __expf(zC[r][0] - rms[r]) + __expf(zC[r][1] - rms[r]) +
             __expf(zC[r][2] - rms[r]) + __expf(zC[r][3] - rms[r]);
      for (int off = 32; off; off >>= 1) s += __shfl_xor(s, off);
      sm[r] = s;
    }
    if (lane == 0) {
#pragma unroll
      for (int r = 0; r < 4; ++r) red[wv * 4 + r] = sm[r];
    }
  }
  __syncthreads();
  if (tid < 4) {
    float s = red[tid];
#pragma unroll
    for (int w = 1; w < 8; ++w) s += red[w * 4 + tid];
    rowoff[tid] = rowmax[tid] + logf(s);
  }
  __syncthreads();

  // write out = z - rowoff, float4 stores from registers
  {
    const float o[4] = {rowoff[0], rowoff[1], rowoff[2], rowoff[3]};
#pragma unroll
    for (int r = 0; r < 4; ++r) {
      float* __restrict__ orow = out + (size_t)(row0 + r) * NN;
      float4 v;
      v.x = zA[r][0] - o[r]; v.y = zA[r][1] - o[r];
      v.z = zA[r][2] - o[r]; v.w = zA[r][3] - o[r];
      *(float4*)(orow + c0) = v;
      v.x = zB[r][0] - o[r]; v.y = zB[r][1] - o[r];
      v.z = zB[r][2] - o[r]; v.w = zB[r][3] - o[r];
      *(float4*)(orow + c1) = v;
      if (act2) {
        v.x = zC[r][0] - o[r]; v.y = zC[r][1] - o[r];
        v.z = zC[r][2] - o[r]; v.w = zC[r][3] - o[r];
        *(float4*)(orow + c2) = v;
      }
    }
  }
}

extern "C" void kernel_launch(void* const* d_in, const int* in_sizes, int n_in,
                              void* d_out, int out_size, void* d_ws, size_t ws_size,
                              hipStream_t stream) {
  const float* x  = (const float*)d_in[0];
  const int*   src = (const int*)d_in[1];
  const int*   dst = (const int*)d_in[2];
  const float* W1 = (const float*)d_in[3];
  const float* b1 = (const float*)d_in[4];
  const float* W2 = (const float*)d_in[5];
  const float* b2 = (const float*)d_in[6];
  float* out = (float*)d_out;

  char* ws = (char*)d_ws;
  int*   cur   = (int*)(ws);                // [0, 20000)
  float* h1    = (float*)(ws + 20000);      // [20000, 340000)
  int*   slots = (int*)(ws + 340000);       // [340000, 2900000)
  float* a1    = (float*)(ws + 2900000);    // [2900000, 3220000)

  // zero cur + h1 (scatter cursors; split-k atomics accumulate into h1)
  hipMemsetAsync(d_ws, 0, 340000, stream);
  k_gemm_scat<<<SCB + GMB, 256, 0, stream>>>(x, W1, h1, src, dst, cur, slots);
  k_gather1<<<NN / 4, 256, 0, stream>>>(slots, cur, b1, h1, a1);
  k_final6<<<NN / 4, 512, 0, stream>>>(slots, cur, a1, W2, b2, out);
}

// Round 20
// 245.591 us; speedup vs baseline: 1.4972x; 1.4972x over previous
//
#include <hip/hip_runtime.h>
#include <math.h>

#define NN 5000
#define NE 160000
#define NF 16
#define KS 640      // k per split (8 splits: 7x640 + 520)
#define WTS 648     // LDS k-stride (bf16): 324 words, %32=4 -> 2-way alias = free
#define CAP 128     // per-node edge bucket capacity (max in-deg ~65 @ lambda=32)
#define SCB 625     // scatter-role blocks (625*256 = 160000 = NE exact)
#define GMB 632     // gemm-role blocks (79 x-tiles * 8 k-splits)

typedef __attribute__((ext_vector_type(8))) short bf16x8;  // 4 VGPRs
typedef __attribute__((ext_vector_type(4))) float f32x4;   // MFMA acc

// ws layout (bytes):
// [0,       20000)   cur   : per-node cursor -> in-degree after scatter (zeroed)
// [20000,   340000)  h1    : x@W1 (split-k atomics -> zeroed)
// [340000,  2900000) slots : bucketed edge sources, slots[d*CAP+pos]=src
// [2900000, 3220000) a1    : relu(agg1(h1)+b1)

__device__ __forceinline__ short f2bf(float f) {  // RNE f32->bf16
  union { float f; unsigned u; } v; v.f = f;
  unsigned r = v.u + 0x7FFFu + ((v.u >> 16) & 1u);
  return (short)(r >> 16);
}

// Merged kernel: blocks [0,SCB) bucket edges by dst; blocks [SCB, SCB+GMB)
// compute h1 = x @ W1 via mfma_f32_16x16x32_bf16 (fp32 acc), split-k x8.
__global__ __launch_bounds__(256) void k_gemm_scat(const float* __restrict__ x,
                                                   const float* __restrict__ w1,
                                                   float* __restrict__ h1,
                                                   const int* __restrict__ src,
                                                   const int* __restrict__ dst,
                                                   int* __restrict__ cur,
                                                   int* __restrict__ slots) {
  __shared__ short wt[NF * WTS];  // 20736 B (unused by scatter role)
  const int bid = blockIdx.x;
  const int tid = threadIdx.x;

  if (bid < SCB) {                // ---- scatter role ----
    const int e = bid * 256 + tid;
    if (e < NE) {
      const int d = dst[e];
      const int pos = atomicAdd(&cur[d], 1);
      if (pos < CAP) slots[d * CAP + pos] = src[e];
    }
    return;                       // uniform per block; no barrier crossed
  }

  // ---- gemm role ----
  const int gb = bid - SCB;       // 0..631
  const int bx = gb % 79;
  const int by = gb / 79;
  const int lane = tid & 63;
  const int wv = tid >> 6;
  const int kb = by * KS;
  const int klen = (NN - kb < KS) ? (NN - kb) : KS;   // 640 or 520
  const int nsteps = (klen + 31) >> 5;                // 20 or 17

  // Stage W1[kb..kb+KS) -> wt[n][kk] transposed bf16, zero-padded past NN.
  for (int kk = tid; kk < KS; kk += 256) {
    const int kg = kb + kk;
    if (kg < NN) {
      const float4* __restrict__ wr = (const float4*)(w1 + (size_t)kg * NF);
      const float4 a = wr[0], b = wr[1], c = wr[2], d = wr[3];
      wt[0 * WTS + kk] = f2bf(a.x);  wt[1 * WTS + kk] = f2bf(a.y);
      wt[2 * WTS + kk] = f2bf(a.z);  wt[3 * WTS + kk] = f2bf(a.w);
      wt[4 * WTS + kk] = f2bf(b.x);  wt[5 * WTS + kk] = f2bf(b.y);
      wt[6 * WTS + kk] = f2bf(b.z);  wt[7 * WTS + kk] = f2bf(b.w);
      wt[8 * WTS + kk] = f2bf(c.x);  wt[9 * WTS + kk] = f2bf(c.y);
      wt[10 * WTS + kk] = f2bf(c.z); wt[11 * WTS + kk] = f2bf(c.w);
      wt[12 * WTS + kk] = f2bf(d.x); wt[13 * WTS + kk] = f2bf(d.y);
      wt[14 * WTS + kk] = f2bf(d.z); wt[15 * WTS + kk] = f2bf(d.w);
    } else {
#pragma unroll
      for (int n = 0; n < NF; ++n) wt[n * WTS + kk] = 0;
    }
  }
  __syncthreads();

  const int tile = bx * 4 + wv;   // 0..315 (313 real)
  const int m0 = tile * 16;
  int arow = m0 + (lane & 15);
  if (arow > NN - 1) arow = NN - 1;       // clamp addr; write guarded below
  const float* __restrict__ xr = x + (size_t)arow * NN + kb;
  const int quad = lane >> 4;
  const short* __restrict__ bp = &wt[(lane & 15) * WTS + quad * 8];

  f32x4 acc = {0.f, 0.f, 0.f, 0.f};
  for (int s = 0; s < nsteps; ++s) {
    const int k0 = s * 32 + quad * 8;     // offset within split (8-aligned)
    bf16x8 a;
    if (kb + k0 < NN) {                   // whole 8-chunk valid (NN%8==0)
      const float4 xa = *(const float4*)(xr + k0);
      const float4 xb = *(const float4*)(xr + k0 + 4);
      a[0] = f2bf(xa.x); a[1] = f2bf(xa.y); a[2] = f2bf(xa.z); a[3] = f2bf(xa.w);
      a[4] = f2bf(xb.x); a[5] = f2bf(xb.y); a[6] = f2bf(xb.z); a[7] = f2bf(xb.w);
    } else {
#pragma unroll
      for (int j = 0; j < 8; ++j) a[j] = 0;
    }
    const bf16x8 b = *(const bf16x8*)(bp + s * 32);  // ds_read_b128
    acc = __builtin_amdgcn_mfma_f32_16x16x32_bf16(a, b, acc, 0, 0, 0);
  }

  const int col = lane & 15;
#pragma unroll
  for (int r = 0; r < 4; ++r) {
    const int orow = m0 + quad * 4 + r;
    if (orow < NN) atomicAdd(&h1[orow * NF + col], acc[r]);
  }
}

// Layer-1 aggregation (gather, no atomics), fused bias+ReLU:
//   a1[v][j] = relu(inv[v]*sum_s inv[s]*h1[s][j] + inv[v]^2*h1[v][j] + b1[j])
__global__ __launch_bounds__(256) void k_gather1(const int* __restrict__ slots,
                                                 const int* __restrict__ cnt,
                                                 const float* __restrict__ bias,
                                                 const float* __restrict__ hin,
                                                 float* __restrict__ outp) {
  const int tid = threadIdx.x;
  const int lane = tid & 63;
  const int wv = tid >> 6;
  const int v = blockIdx.x * 4 + wv;
  if (v >= NN) return;
  const int j = lane & 15;
  const int eg = lane >> 4;                 // edge subgroup 0..3
  int deg = cnt[v];
  if (deg > CAP) deg = CAP;
  const int* __restrict__ sl = slots + v * CAP;

  float acc = 0.f;
  int base = 0;
  for (; base + 8 <= deg; base += 8) {      // 2 independent chains per iter
    const int s0 = sl[base + eg];
    const int s1 = sl[base + 4 + eg];
    const float iv0 = rsqrtf((float)cnt[s0] + 1.0f);
    const float iv1 = rsqrtf((float)cnt[s1] + 1.0f);
    acc += iv0 * hin[s0 * NF + j];
    acc += iv1 * hin[s1 * NF + j];
  }
  for (; base < deg; base += 4) {
    const int idx = base + eg;
    if (idx < deg) {
      const int s = sl[idx];
      acc += rsqrtf((float)cnt[s] + 1.0f) * hin[s * NF + j];
    }
  }
  acc += __shfl_xor(acc, 16);
  acc += __shfl_xor(acc, 32);

  if (lane < 16) {
    const float ivv = rsqrtf((float)deg + 1.0f);
    float r = ivv * acc + ivv * ivv * hin[v * NF + j];
    outp[v * NF + j] = fmaxf(r + bias[j], 0.f);
  }
}

// Fused layer-2 aggregation + final GEMM + log_softmax.
// REVERT to the round-9 k_final3 structure (LDS zs, col-per-thread, w[16]
// register reuse across rows -- measured 65us, VGPR 52, FETCH 5MB, clean),
// with ONE change: ROWS 4->2, 512 threads, zs 40KB -> 3 blocks/CU (24
// waves vs 16) to lift the 37% occupancy that bounds it. All-register-z
// designs (rounds 10-18) spill at the allocator's 128 cap -- abandoned.
__global__ __launch_bounds__(512) void k_final7(const int* __restrict__ slots,
                                                const int* __restrict__ cnt,
                                                const float* __restrict__ a1,
                                                const float* __restrict__ w2,
                                                const float* __restrict__ b2,
                                                float* __restrict__ out) {
  __shared__ float zs[2 * NN];      // 40000 B
  __shared__ float pp[8][NF];       // per-wave gather partials
  __shared__ float gsh[2 * NF];
  __shared__ float red[8 * 2];
  __shared__ float rowmax[2];
  __shared__ float rowoff[2];
  const int tid = threadIdx.x;
  const int lane = tid & 63;
  const int wv = tid >> 6;          // 0..7
  const int row0 = blockIdx.x * 2;

  // ---- phase 1: gather g2 rows (4 waves/node, 16 edge-subgroups) ----
  {
    const int r = wv >> 2;                          // node 0..1
    const int v = row0 + r;
    const int j = lane & 15;
    const int sg = ((wv & 3) << 2) | (lane >> 4);   // 0..15, stride 16
    int deg = cnt[v];
    if (deg > CAP) deg = CAP;
    const int* __restrict__ sl = slots + v * CAP;
    float acc = 0.f;
    for (int idx = sg; idx < deg; idx += 16) {
      const int s = sl[idx];
      acc += rsqrtf((float)cnt[s] + 1.0f) * a1[s * NF + j];
    }
    acc += __shfl_xor(acc, 16);
    acc += __shfl_xor(acc, 32);
    if (lane < 16) pp[wv][j] = acc;
  }
  __syncthreads();
  if (tid < 32) {
    const int r = tid >> 4, j = tid & 15;
    const int v = row0 + r;
    int deg = cnt[v];
    if (deg > CAP) deg = CAP;
    const float ivv = rsqrtf((float)deg + 1.0f);
    const float acc = pp[r * 4 + 0][j] + pp[r * 4 + 1][j] +
                      pp[r * 4 + 2][j] + pp[r * 4 + 3][j];
    gsh[r * NF + j] = ivv * acc + ivv * ivv * a1[v * NF + j];
  }
  __syncthreads();

  // ---- phase 2: z = g2 @ W2 + b2, col-per-thread, w[] shared across rows
  float g[2][NF];
#pragma unroll
  for (int r = 0; r < 2; ++r)
#pragma unroll
    for (int k = 0; k < NF; ++k) g[r][k] = gsh[r * NF + k];

  float mx[2] = {-1e30f, -1e30f};
  for (int jc = tid; jc < NN; jc += 512) {
    float w[NF];
#pragma unroll
    for (int k = 0; k < NF; ++k) w[k] = w2[k * NN + jc];
    const float bb = b2[jc];
#pragma unroll
    for (int r = 0; r < 2; ++r) {
      float z = bb;
#pragma unroll
      for (int k = 0; k < NF; ++k) z = fmaf(g[r][k], w[k], z);
      zs[r * NN + jc] = z;
      mx[r] = fmaxf(mx[r], z);
    }
  }
#pragma unroll
  for (int r = 0; r < 2; ++r) {
    float m = mx[r];
    for (int off = 32; off; off >>= 1) m = fmaxf(m, __shfl_xor(m, off));
    if (lane == 0) red[wv * 2 + r] = m;
  }
  __syncthreads();
  if (tid < 2) {
    float m = red[tid];
#pragma unroll
    for (int w = 1; w < 8; ++w) m = fmaxf(m, red[w * 2 + tid]);
    rowmax[tid] = m;
  }
  __syncthreads();
  const float rm0 = rowmax[0], rm1 = rowmax[1];

  float sm[2] = {0.f, 0.f};
  for (int jc = tid; jc < NN; jc += 512) {
    sm[0] += __expf(zs[0 * NN + jc] - rm0);
    sm[1] += __expf(zs[1 * NN + jc] - rm1);
  }
#pragma unroll
  for (int r = 0; r < 2; ++r) {
    float s = sm[r];
    for (int off = 32; off; off >>= 1) s += __shfl_xor(s, off);
    if (lane == 0) red[wv * 2 + r] = s;
  }
  __syncthreads();
  if (tid < 2) {
    float s = red[tid];
#pragma unroll
    for (int w = 1; w < 8; ++w) s += red[w * 2 + tid];
    rowoff[tid] = rowmax[tid] + logf(s);
  }
  __syncthreads();
  const float o0 = rowoff[0], o1 = rowoff[1];
  for (int jc = tid; jc < NN; jc += 512) {
    out[(size_t)(row0 + 0) * NN + jc] = zs[0 * NN + jc] - o0;
    out[(size_t)(row0 + 1) * NN + jc] = zs[1 * NN + jc] - o1;
  }
}

extern "C" void kernel_launch(void* const* d_in, const int* in_sizes, int n_in,
                              void* d_out, int out_size, void* d_ws, size_t ws_size,
                              hipStream_t stream) {
  const float* x  = (const float*)d_in[0];
  const int*   src = (const int*)d_in[1];
  const int*   dst = (const int*)d_in[2];
  const float* W1 = (const float*)d_in[3];
  const float* b1 = (const float*)d_in[4];
  const float* W2 = (const float*)d_in[5];
  const float* b2 = (const float*)d_in[6];
  float* out = (float*)d_out;

  char* ws = (char*)d_ws;
  int*   cur   = (int*)(ws);                // [0, 20000)
  float* h1    = (float*)(ws + 20000);      // [20000, 340000)
  int*   slots = (int*)(ws + 340000);       // [340000, 2900000)
  float* a1    = (float*)(ws + 2900000);    // [2900000, 3220000)

  // zero cur + h1 (scatter cursors; split-k atomics accumulate into h1)
  hipMemsetAsync(d_ws, 0, 340000, stream);
  k_gemm_scat<<<SCB + GMB, 256, 0, stream>>>(x, W1, h1, src, dst, cur, slots);
  k_gather1<<<NN / 4, 256, 0, stream>>>(slots, cur, b1, h1, a1);
  k_final7<<<NN / 2, 512, 0, stream>>>(slots, cur, a1, W2, b2, out);
}